// Round 8
// baseline (284.278 us; speedup 1.0000x reference)
//
#include <hip/hip_runtime.h>

#define N_NODES 50000
#define N_EDGES 640000
#define HD 128
#define TILE_N 128
#define NSCB 196   // ceil(50000/256)
#define NTILE 391  // ceil(50000/128)

typedef short bf16x8 __attribute__((ext_vector_type(8)));      // 8 bf16 = 4 VGPR (guide §3)
typedef float f32x4 __attribute__((ext_vector_type(4)));
typedef unsigned short u16x8 __attribute__((ext_vector_type(8)));
typedef unsigned short u16x4 __attribute__((ext_vector_type(4)));

__device__ __forceinline__ unsigned short f2bf(float f) {  // RNE f32 -> bf16
  unsigned u = __float_as_uint(f);
  return (unsigned short)((u + 0x7fffu + ((u >> 16) & 1u)) >> 16);
}
__device__ __forceinline__ float bf2f(unsigned short h) {
  return __uint_as_float(((unsigned)h) << 16);
}
// byte offset of logical (row, 16B-unit u) in a [128 rows][128 bf16] LDS tile.
// XOR swizzle spreads same-u column reads across 8 bank-quads (2-way = free).
// SINGLE source of truth for this layout (rule #21).
__device__ __forceinline__ int swzb(int row, int u) {
  return row * 256 + ((u ^ (row & 7)) << 4);
}

// ---- MFMA building blocks: 4 waves, wave tile 64x64, 16x16x32 bf16 ----
__device__ __forceinline__ void load_A(const char* Ash, int lane, int wr, bf16x8 A[4][4]) {
  const int l15 = lane & 15, l4 = lane >> 4;
#pragma unroll
  for (int rt = 0; rt < 4; ++rt)
#pragma unroll
    for (int kk = 0; kk < 4; ++kk)
      A[rt][kk] = *(const bf16x8*)(Ash + swzb(wr * 64 + rt * 16 + l15, kk * 4 + l4));
}

__device__ __forceinline__ void mfma_AB(const bf16x8 A[4][4], const char* Bsh,
                                        int lane, int wc, f32x4 acc[4][4]) {
  const int l15 = lane & 15, l4 = lane >> 4;
#pragma unroll
  for (int ct = 0; ct < 4; ++ct) {
    bf16x8 B[4];
#pragma unroll
    for (int kk = 0; kk < 4; ++kk)
      B[kk] = *(const bf16x8*)(Bsh + swzb(wc * 64 + ct * 16 + l15, kk * 4 + l4));
#pragma unroll
    for (int rt = 0; rt < 4; ++rt)
#pragma unroll
      for (int kk = 0; kk < 4; ++kk)
        acc[rt][ct] =
            __builtin_amdgcn_mfma_f32_16x16x32_bf16(A[rt][kk], B[kk], acc[rt][ct], 0, 0, 0);
  }
}

// C/D layout (m89-verified): col=lane&15 (+16ct+64wc), row=(lane>>4)*4+e (+16rt+64wr).
__device__ __forceinline__ void scatter_acc(char* Tsh, int lane, int wr, int wc,
                                            const f32x4 acc[4][4]) {
  const int l15 = lane & 15, l4 = lane >> 4;
#pragma unroll
  for (int rt = 0; rt < 4; ++rt)
#pragma unroll
    for (int ct = 0; ct < 4; ++ct) {
      int c = wc * 64 + ct * 16 + l15;
#pragma unroll
      for (int e = 0; e < 4; ++e) {
        int r = wr * 64 + rt * 16 + l4 * 4 + e;
        *(unsigned short*)(Tsh + swzb(r, c >> 3) + (c & 7) * 2) = f2bf(acc[rt][ct][e]);
      }
    }
}

__device__ __forceinline__ void copy_out(const char* Tsh, unsigned short* __restrict__ g,
                                         int bnode0, int tid) {
#pragma unroll
  for (int c = 0; c < 8; ++c) {
    int ul = c * 256 + tid;
    int row = ul >> 4, u = ul & 15;
    if (bnode0 + row < N_NODES)
      *(u16x8*)(g + (size_t)(bnode0 + row) * HD + u * 8) = *(const u16x8*)(Tsh + swzb(row, u));
  }
}

// bf16 global [rows][128] -> swizzled LDS tile
__device__ __forceinline__ void stage_bf(const unsigned short* __restrict__ src, char* Tsh,
                                         int bnode0, int tid, bool guard) {
#pragma unroll
  for (int c = 0; c < 8; ++c) {
    int ul = c * 256 + tid;
    int row = ul >> 4, u = ul & 15;
    u16x8 v = {0, 0, 0, 0, 0, 0, 0, 0};
    if (!guard || (bnode0 + row < N_NODES))
      v = *(const u16x8*)(src + (size_t)(bnode0 + row) * HD + u * 8);
    *(u16x8*)(Tsh + swzb(row, u)) = v;
  }
}

// f32 global [rows][128] -> bf16 swizzled LDS tile
__device__ __forceinline__ void stage_xf(const float* __restrict__ src, char* Tsh,
                                         int bnode0, int tid) {
#pragma unroll
  for (int c = 0; c < 16; ++c) {
    int f4 = c * 256 + tid;
    int row = f4 >> 5, c4 = f4 & 31;
    float4 v = make_float4(0.f, 0.f, 0.f, 0.f);
    if (bnode0 + row < N_NODES) v = ((const float4*)src)[(size_t)(bnode0 + row) * 32 + c4];
    u16x4 p;
    p[0] = f2bf(v.x); p[1] = f2bf(v.y); p[2] = f2bf(v.z); p[3] = f2bf(v.w);
    *(u16x4*)(Tsh + swzb(row, c4 >> 1) + (c4 & 1) * 8) = p;
  }
}

// ---- one-shot: blocks 0-4: W^T bf16 slices [WpT,WmaT,WmbT,Wu0T,Wu1T] each [128n][128k];
//      blocks 5-102: zero the deg/gsum/done region (50176 ints, unguarded int4). ----
__global__ __launch_bounds__(128) void k_prew(const float* __restrict__ Wp,
                                              const float* __restrict__ Wm,
                                              const float* __restrict__ Wu,
                                              unsigned short* __restrict__ WT,
                                              int* __restrict__ zbase) {
  if (blockIdx.x >= 5) {
    int idx = (blockIdx.x - 5) * 512 + threadIdx.x * 4;
    *(int4*)(zbase + idx) = make_int4(0, 0, 0, 0);
    return;
  }
  const int s = blockIdx.x;
  const float* src = (s == 0) ? Wp : (s == 1) ? Wm : (s == 2) ? (Wm + HD * HD)
                     : (s == 3) ? Wu : (Wu + HD * HD);
  const int n = threadIdx.x;
  unsigned short* dst = WT + (size_t)s * HD * HD + (size_t)n * HD;
  for (int kc = 0; kc < HD; kc += 8) {
    u16x8 p;
#pragma unroll
    for (int j = 0; j < 8; ++j) p[j] = f2bf(src[(size_t)(kc + j) * HD + n]);
    *(u16x8*)(dst + kc) = p;
  }
}

// h0 = x@Wp+bp ; a = h0@Wm[:H] ; b = h0@Wm[H:]+bm   (all bf16 out)
__global__ __launch_bounds__(256, 2) void k_proj(
    const float* __restrict__ x, const unsigned short* __restrict__ WT,
    const float* __restrict__ bp, const float* __restrict__ bm,
    unsigned short* __restrict__ h0, unsigned short* __restrict__ a,
    unsigned short* __restrict__ b) {
  __shared__ char Ssh[32768];
  __shared__ char Wsh[32768];
  const int tid = threadIdx.x, lane = tid & 63, wid = tid >> 6;
  const int wr = wid >> 1, wc = wid & 1, l15 = lane & 15;
  const int bnode0 = blockIdx.x * TILE_N;

  stage_xf(x, Ssh, bnode0, tid);
  stage_bf(WT, Wsh, 0, tid, false);  // WpT
  __syncthreads();

  bf16x8 A[4][4];
  f32x4 acc[4][4];
  load_A(Ssh, lane, wr, A);
#pragma unroll
  for (int ct = 0; ct < 4; ++ct) {
    float bv = bp[wc * 64 + ct * 16 + l15];
    f32x4 sv = {bv, bv, bv, bv};
#pragma unroll
    for (int rt = 0; rt < 4; ++rt) acc[rt][ct] = sv;
  }
  mfma_AB(A, Wsh, lane, wc, acc);          // h0
  __syncthreads();                          // x reads done
  scatter_acc(Ssh, lane, wr, wc, acc);      // h0 -> Ssh
  stage_bf(WT + 1 * HD * HD, Wsh, 0, tid, false);  // WmaT
  __syncthreads();
  copy_out(Ssh, h0, bnode0, tid);
  load_A(Ssh, lane, wr, A);                 // h0 frags (kept for a AND b)
#pragma unroll
  for (int ct = 0; ct < 4; ++ct) {
    f32x4 z = {0.f, 0.f, 0.f, 0.f};
#pragma unroll
    for (int rt = 0; rt < 4; ++rt) acc[rt][ct] = z;
  }
  mfma_AB(A, Wsh, lane, wc, acc);          // a
  __syncthreads();                          // copy_out(h0)+load_A done everywhere
  scatter_acc(Ssh, lane, wr, wc, acc);      // a -> Ssh
  stage_bf(WT + 2 * HD * HD, Wsh, 0, tid, false);  // WmbT
  __syncthreads();
  copy_out(Ssh, a, bnode0, tid);
#pragma unroll
  for (int ct = 0; ct < 4; ++ct) {
    float bv = bm[wc * 64 + ct * 16 + l15];
    f32x4 sv = {bv, bv, bv, bv};
#pragma unroll
    for (int rt = 0; rt < 4; ++rt) acc[rt][ct] = sv;
  }
  mfma_AB(A, Wsh, lane, wc, acc);          // b (A regs reused)
  __syncthreads();                          // copy_out(a) done everywhere
  scatter_acc(Ssh, lane, wr, wc, acc);      // b -> Ssh
  __syncthreads();
  copy_out(Ssh, b, bnode0, tid);
}

// pos_e[e] = slot of edge e within its destination's segment (single atomic pass)
__global__ void k_hist(const int* __restrict__ dst, int* __restrict__ deg,
                       int* __restrict__ pos_e) {
  int e = blockIdx.x * 256 + threadIdx.x;
  if (e < N_EDGES) pos_e[e] = atomicAdd(&deg[dst[e]], 1);
}

__global__ __launch_bounds__(256) void k_scan1(const int* __restrict__ deg,
                                               int* __restrict__ bsum) {
  __shared__ int sh[256];
  int i = blockIdx.x * 256 + threadIdx.x;
  sh[threadIdx.x] = (i < N_NODES) ? deg[i] : 0;
  __syncthreads();
  for (int off = 128; off > 0; off >>= 1) {
    if (threadIdx.x < off) sh[threadIdx.x] += sh[threadIdx.x + off];
    __syncthreads();
  }
  if (threadIdx.x == 0) bsum[blockIdx.x] = sh[0];
}

__global__ __launch_bounds__(256) void k_scan2(const int* __restrict__ bsum,
                                               int* __restrict__ boff,
                                               int* __restrict__ row_start) {
  __shared__ int sh[256];
  int t = threadIdx.x;
  int v = (t < NSCB) ? bsum[t] : 0;
  sh[t] = v;
  __syncthreads();
  for (int off = 1; off < 256; off <<= 1) {
    int add = (t >= off) ? sh[t - off] : 0;
    __syncthreads();
    sh[t] += add;
    __syncthreads();
  }
  if (t < NSCB) boff[t] = sh[t] - v;
  if (t == 255) row_start[N_NODES] = sh[255];
}

__global__ __launch_bounds__(256) void k_scan3(const int* __restrict__ deg,
                                               const int* __restrict__ boff,
                                               int* __restrict__ row_start) {
  __shared__ int sh[256];
  int t = threadIdx.x;
  int i = blockIdx.x * 256 + t;
  int v = (i < N_NODES) ? deg[i] : 0;
  sh[t] = v;
  __syncthreads();
  for (int off = 1; off < 256; off <<= 1) {
    int add = (t >= off) ? sh[t - off] : 0;
    __syncthreads();
    sh[t] += add;
    __syncthreads();
  }
  if (i < N_NODES) row_start[i] = boff[blockIdx.x] + sh[t] - v;
}

// atomic-free scatter: slot precomputed in k_hist
__global__ void k_scatter(const int* __restrict__ src, const int* __restrict__ dst,
                          const int* __restrict__ pos_e, const int* __restrict__ row_start,
                          int* __restrict__ es) {
  int e = blockIdx.x * 256 + threadIdx.x;
  if (e < N_EDGES) {
    int d = dst[e];
    es[row_start[d] + pos_e[e]] = src[e];
  }
}

// Fused: pool (segment-mean of relu(a[src]+b[n])) -> LDS tile -> upd GEMMs ->
// residual+relu -> LayerNorm -> graph-sum atomics -> last block: out = g@Wd+bd.
__global__ __launch_bounds__(256, 2) void k_aggupd(
    const unsigned short* __restrict__ h0, const unsigned short* __restrict__ a,
    const unsigned short* __restrict__ b, const int* __restrict__ es,
    const int* __restrict__ row_start, const unsigned short* __restrict__ WT,
    const float* __restrict__ bu, const float* __restrict__ gamma,
    const float* __restrict__ beta, const float* __restrict__ Wd,
    const float* __restrict__ bd, float* __restrict__ gsum,
    int* __restrict__ done, float* __restrict__ out) {
  __shared__ char Ssh[32768];
  __shared__ char Wsh[32768];
  __shared__ int lastflag;
  const int tid = threadIdx.x, lane = tid & 63, wid = tid >> 6;
  const int wr = wid >> 1, wc = wid & 1, l15 = lane & 15, l4 = lane >> 4;
  const int bnode0 = blockIdx.x * TILE_N;

  // ---- Phase A: pool 32 nodes per wave straight into Ssh (pooled tile) ----
  stage_bf(WT + 4 * HD * HD, Wsh, 0, tid, false);  // Wu1T (overlaps gathers)
  for (int rr = 0; rr < 32; ++rr) {
    const int row = wid * 32 + rr;
    const int n = bnode0 + row;
    unsigned packed = 0;
    if (n < N_NODES) {
      const int s = row_start[n];
      const int e = row_start[n + 1];
      const unsigned bv = ((const unsigned*)(b + (size_t)n * HD))[lane];
      const float bx = bf2f((unsigned short)(bv & 0xffffu));
      const float by = bf2f((unsigned short)(bv >> 16));
      float ax = 0.f, ay = 0.f;
      int i = s;
      for (; i + 8 <= e; i += 8) {
        unsigned av[8];
#pragma unroll
        for (int j = 0; j < 8; ++j)
          av[j] = ((const unsigned*)(a + (size_t)es[i + j] * HD))[lane];
#pragma unroll
        for (int j = 0; j < 8; ++j) {
          ax += fmaxf(bf2f((unsigned short)(av[j] & 0xffffu)) + bx, 0.f);
          ay += fmaxf(bf2f((unsigned short)(av[j] >> 16)) + by, 0.f);
        }
      }
      for (; i + 2 <= e; i += 2) {
        unsigned a0 = ((const unsigned*)(a + (size_t)es[i] * HD))[lane];
        unsigned a1 = ((const unsigned*)(a + (size_t)es[i + 1] * HD))[lane];
        ax += fmaxf(bf2f((unsigned short)(a0 & 0xffffu)) + bx, 0.f);
        ay += fmaxf(bf2f((unsigned short)(a0 >> 16)) + by, 0.f);
        ax += fmaxf(bf2f((unsigned short)(a1 & 0xffffu)) + bx, 0.f);
        ay += fmaxf(bf2f((unsigned short)(a1 >> 16)) + by, 0.f);
      }
      for (; i < e; ++i) {
        unsigned a0 = ((const unsigned*)(a + (size_t)es[i] * HD))[lane];
        ax += fmaxf(bf2f((unsigned short)(a0 & 0xffffu)) + bx, 0.f);
        ay += fmaxf(bf2f((unsigned short)(a0 >> 16)) + by, 0.f);
      }
      const float inv = 1.f / fmaxf((float)(e - s), 1.f);
      packed = (unsigned)f2bf(ax * inv) | ((unsigned)f2bf(ay * inv) << 16);
    }
    *(unsigned*)(Ssh + swzb(row, lane >> 2) + (lane & 3) * 4) = packed;
  }
  __syncthreads();

  // ---- Phase B: upd = pooled@Wu1 + h0@Wu0 + bu ----
  bf16x8 A[4][4];
  f32x4 acc[4][4];
  load_A(Ssh, lane, wr, A);  // pooled frags
#pragma unroll
  for (int ct = 0; ct < 4; ++ct) {
    float bv = bu[wc * 64 + ct * 16 + l15];
    f32x4 sv = {bv, bv, bv, bv};
#pragma unroll
    for (int rt = 0; rt < 4; ++rt) acc[rt][ct] = sv;
  }
  mfma_AB(A, Wsh, lane, wc, acc);  // pooled@Wu1 + bu
  __syncthreads();                 // pooled-tile reads done
  stage_bf(h0, Ssh, bnode0, tid, true);
  stage_bf(WT + 3 * HD * HD, Wsh, 0, tid, false);  // Wu0T
  __syncthreads();
  load_A(Ssh, lane, wr, A);
  mfma_AB(A, Wsh, lane, wc, acc);  // += h0@Wu0
  __syncthreads();                 // Wsh free for partials

  // residual + relu + LayerNorm + masked graph partial
  float rsum[4][4], rsq[4][4];
#pragma unroll
  for (int rt = 0; rt < 4; ++rt)
#pragma unroll
    for (int e = 0; e < 4; ++e) {
      int r = wr * 64 + rt * 16 + l4 * 4 + e;
      float srow = 0.f, qrow = 0.f;
#pragma unroll
      for (int ct = 0; ct < 4; ++ct) {
        int c = wc * 64 + ct * 16 + l15;
        float hv = bf2f(*(const unsigned short*)(Ssh + swzb(r, c >> 3) + (c & 7) * 2));
        float v = fmaxf(hv + acc[rt][ct][e], 0.f);
        acc[rt][ct][e] = v;
        srow += v;
        qrow += v * v;
      }
#pragma unroll
      for (int m = 1; m < 16; m <<= 1) {
        srow += __shfl_xor(srow, m);
        qrow += __shfl_xor(qrow, m);
      }
      rsum[rt][e] = srow;
      rsq[rt][e] = qrow;
    }
  float* pS = (float*)Wsh;          // [128][2]
  float* pQ = (float*)(Wsh + 1024);
  if (l15 == 0) {
#pragma unroll
    for (int rt = 0; rt < 4; ++rt)
#pragma unroll
      for (int e = 0; e < 4; ++e) {
        int r = wr * 64 + rt * 16 + l4 * 4 + e;
        pS[r * 2 + wc] = rsum[rt][e];
        pQ[r * 2 + wc] = rsq[rt][e];
      }
  }
  __syncthreads();

  float g4[4], b4[4];
#pragma unroll
  for (int ct = 0; ct < 4; ++ct) {
    int c = wc * 64 + ct * 16 + l15;
    g4[ct] = gamma[c];
    b4[ct] = beta[c];
  }
  float gp[4] = {0.f, 0.f, 0.f, 0.f};
#pragma unroll
  for (int rt = 0; rt < 4; ++rt)
#pragma unroll
    for (int e = 0; e < 4; ++e) {
      int r = wr * 64 + rt * 16 + l4 * 4 + e;
      float s = pS[r * 2] + pS[r * 2 + 1];
      float q = pQ[r * 2] + pQ[r * 2 + 1];
      float mu = s * (1.f / 128.f);
      float var = q * (1.f / 128.f) - mu * mu;
      float rs = rsqrtf(var + 1e-6f);
      bool valid = (bnode0 + r) < N_NODES;
#pragma unroll
      for (int ct = 0; ct < 4; ++ct) {
        float v = (acc[rt][ct][e] - mu) * rs * g4[ct] + b4[ct];
        if (valid) gp[ct] += v;
      }
    }
#pragma unroll
  for (int ct = 0; ct < 4; ++ct) {
    gp[ct] += __shfl_xor(gp[ct], 16);
    gp[ct] += __shfl_xor(gp[ct], 32);
  }
  if (lane < 16) {
#pragma unroll
    for (int ct = 0; ct < 4; ++ct) atomicAdd(&gsum[wc * 64 + ct * 16 + lane], gp[ct]);
  }

  // ---- last block computes the graph head: out = (gsum/N)@Wd + bd ----
  __threadfence();
  __syncthreads();
  if (tid == 0) lastflag = (atomicAdd(done, 1) == gridDim.x - 1) ? 1 : 0;
  __syncthreads();
  if (lastflag) {
    __threadfence();
    if (tid < 32) {
      float acc2 = bd[tid];
      const float invN = 1.f / (float)N_NODES;
      for (int d = 0; d < HD; ++d) acc2 = fmaf(gsum[d] * invN, Wd[d * 32 + tid], acc2);
      out[tid] = acc2;
    }
  }
}

extern "C" void kernel_launch(void* const* d_in, const int* in_sizes, int n_in,
                              void* d_out, int out_size, void* d_ws, size_t ws_size,
                              hipStream_t stream) {
  (void)in_sizes; (void)n_in; (void)out_size; (void)ws_size;
  const float* x    = (const float*)d_in[0];
  const int* esrc   = (const int*)d_in[1];
  const int* edst   = (const int*)d_in[2];
  const float* Wp   = (const float*)d_in[3];
  const float* bp   = (const float*)d_in[4];
  const float* Wm   = (const float*)d_in[5];
  const float* bm   = (const float*)d_in[6];
  const float* Wu   = (const float*)d_in[7];
  const float* bu   = (const float*)d_in[8];
  const float* gam  = (const float*)d_in[9];
  const float* bet  = (const float*)d_in[10];
  const float* Wd   = (const float*)d_in[11];
  const float* bd   = (const float*)d_in[12];
  float* out = (float*)d_out;

  char* ws = (char*)d_ws;
  size_t off = 0;
  unsigned short* WT = (unsigned short*)(ws + off); off += 5 * (size_t)HD * HD * 2;  // 160KB
  unsigned short* h0 = (unsigned short*)(ws + off); off += (size_t)N_NODES * HD * 2;
  unsigned short* a  = (unsigned short*)(ws + off); off += (size_t)N_NODES * HD * 2;
  unsigned short* b  = (unsigned short*)(ws + off); off += (size_t)N_NODES * HD * 2;
  int* es    = (int*)(ws + off); off += (size_t)N_EDGES * 4;
  int* pos_e = (int*)(ws + off); off += (size_t)N_EDGES * 4;
  // zero region: deg[50000] + gsum[128] + done[1] + pad = 50176 ints (98*512)
  int* zbase = (int*)(ws + off);
  int* deg   = zbase;
  float* gsum = (float*)(zbase + N_NODES);
  int* done  = zbase + N_NODES + 128;
  off += (size_t)50176 * 4;
  int* row_start = (int*)(ws + off); off += (size_t)(N_NODES + 1) * 4;
  int* bsum = (int*)(ws + off); off += (size_t)NSCB * 4;
  int* boff = (int*)(ws + off); off += (size_t)NSCB * 4;

  k_prew<<<103, 128, 0, stream>>>(Wp, Wm, Wu, WT, zbase);
  k_proj<<<NTILE, 256, 0, stream>>>(x, WT, bp, bm, h0, a, b);
  k_hist<<<(N_EDGES + 255) / 256, 256, 0, stream>>>(edst, deg, pos_e);
  k_scan1<<<NSCB, 256, 0, stream>>>(deg, bsum);
  k_scan2<<<1, 256, 0, stream>>>(bsum, boff, row_start);
  k_scan3<<<NSCB, 256, 0, stream>>>(deg, boff, row_start);
  k_scatter<<<(N_EDGES + 255) / 256, 256, 0, stream>>>(esrc, edst, pos_e, row_start, es);
  k_aggupd<<<NTILE, 256, 0, stream>>>(h0, a, b, es, row_start, WT, bu, gam, bet,
                                      Wd, bd, gsum, done, out);
}

// Round 10
// 231.978 us; speedup vs baseline: 1.2255x; 1.2255x over previous
//
#include <hip/hip_runtime.h>

#define N_NODES 50000
#define N_EDGES 640000
#define HD 128
#define TILE_N 128
#define NSCB 196   // ceil(50000/256)
#define NTILE 391  // ceil(50000/128)
#define HB 313     // hist blocks fused into k_projhist (313*256*8 >= 640000)

typedef short bf16x8 __attribute__((ext_vector_type(8)));      // 8 bf16 = 4 VGPR (guide §3)
typedef float f32x4 __attribute__((ext_vector_type(4)));
typedef unsigned short u16x8 __attribute__((ext_vector_type(8)));
typedef unsigned short u16x4 __attribute__((ext_vector_type(4)));

__device__ __forceinline__ unsigned short f2bf(float f) {  // RNE f32 -> bf16
  unsigned u = __float_as_uint(f);
  return (unsigned short)((u + 0x7fffu + ((u >> 16) & 1u)) >> 16);
}
__device__ __forceinline__ float bf2f(unsigned short h) {
  return __uint_as_float(((unsigned)h) << 16);
}
// byte offset of logical (row, 16B-unit u) in a [128 rows][128 bf16] LDS tile.
// XOR swizzle spreads same-u column reads across 8 bank-quads (2-way = free).
// SINGLE source of truth for this layout (rule #21).
__device__ __forceinline__ int swzb(int row, int u) {
  return row * 256 + ((u ^ (row & 7)) << 4);
}

// ---- MFMA building blocks: 4 waves, wave tile 64x64, 16x16x32 bf16 ----
__device__ __forceinline__ void load_A(const char* Ash, int lane, int wr, bf16x8 A[4][4]) {
  const int l15 = lane & 15, l4 = lane >> 4;
#pragma unroll
  for (int rt = 0; rt < 4; ++rt)
#pragma unroll
    for (int kk = 0; kk < 4; ++kk)
      A[rt][kk] = *(const bf16x8*)(Ash + swzb(wr * 64 + rt * 16 + l15, kk * 4 + l4));
}

__device__ __forceinline__ void mfma_AB(const bf16x8 A[4][4], const char* Bsh,
                                        int lane, int wc, f32x4 acc[4][4]) {
  const int l15 = lane & 15, l4 = lane >> 4;
#pragma unroll
  for (int ct = 0; ct < 4; ++ct) {
    bf16x8 B[4];
#pragma unroll
    for (int kk = 0; kk < 4; ++kk)
      B[kk] = *(const bf16x8*)(Bsh + swzb(wc * 64 + ct * 16 + l15, kk * 4 + l4));
#pragma unroll
    for (int rt = 0; rt < 4; ++rt)
#pragma unroll
      for (int kk = 0; kk < 4; ++kk)
        acc[rt][ct] =
            __builtin_amdgcn_mfma_f32_16x16x32_bf16(A[rt][kk], B[kk], acc[rt][ct], 0, 0, 0);
  }
}

// C/D layout (m89-verified): col=lane&15 (+16ct+64wc), row=(lane>>4)*4+e (+16rt+64wr).
__device__ __forceinline__ void scatter_acc(char* Tsh, int lane, int wr, int wc,
                                            const f32x4 acc[4][4]) {
  const int l15 = lane & 15, l4 = lane >> 4;
#pragma unroll
  for (int rt = 0; rt < 4; ++rt)
#pragma unroll
    for (int ct = 0; ct < 4; ++ct) {
      int c = wc * 64 + ct * 16 + l15;
#pragma unroll
      for (int e = 0; e < 4; ++e) {
        int r = wr * 64 + rt * 16 + l4 * 4 + e;
        *(unsigned short*)(Tsh + swzb(r, c >> 3) + (c & 7) * 2) = f2bf(acc[rt][ct][e]);
      }
    }
}

__device__ __forceinline__ void copy_out(const char* Tsh, unsigned short* __restrict__ g,
                                         int bnode0, int tid) {
#pragma unroll
  for (int c = 0; c < 8; ++c) {
    int ul = c * 256 + tid;
    int row = ul >> 4, u = ul & 15;
    if (bnode0 + row < N_NODES)
      *(u16x8*)(g + (size_t)(bnode0 + row) * HD + u * 8) = *(const u16x8*)(Tsh + swzb(row, u));
  }
}

// bf16 global [rows][128] -> swizzled LDS tile
__device__ __forceinline__ void stage_bf(const unsigned short* __restrict__ src, char* Tsh,
                                         int bnode0, int tid, bool guard) {
#pragma unroll
  for (int c = 0; c < 8; ++c) {
    int ul = c * 256 + tid;
    int row = ul >> 4, u = ul & 15;
    u16x8 v = {0, 0, 0, 0, 0, 0, 0, 0};
    if (!guard || (bnode0 + row < N_NODES))
      v = *(const u16x8*)(src + (size_t)(bnode0 + row) * HD + u * 8);
    *(u16x8*)(Tsh + swzb(row, u)) = v;
  }
}

// f32 global [rows][128] -> bf16 swizzled LDS tile
__device__ __forceinline__ void stage_xf(const float* __restrict__ src, char* Tsh,
                                         int bnode0, int tid) {
#pragma unroll
  for (int c = 0; c < 16; ++c) {
    int f4 = c * 256 + tid;
    int row = f4 >> 5, c4 = f4 & 31;
    float4 v = make_float4(0.f, 0.f, 0.f, 0.f);
    if (bnode0 + row < N_NODES) v = ((const float4*)src)[(size_t)(bnode0 + row) * 32 + c4];
    u16x4 p;
    p[0] = f2bf(v.x); p[1] = f2bf(v.y); p[2] = f2bf(v.z); p[3] = f2bf(v.w);
    *(u16x4*)(Tsh + swzb(row, c4 >> 1) + (c4 & 1) * 8) = p;
  }
}

// ---- one-shot: blocks 0-4: W^T bf16 slices [WpT,WmaT,WmbT,Wu0T,Wu1T] each [128n][128k];
//      blocks 5-102: zero the deg/gsum/done region (50176 ints, unguarded int4). ----
__global__ __launch_bounds__(128) void k_prew(const float* __restrict__ Wp,
                                              const float* __restrict__ Wm,
                                              const float* __restrict__ Wu,
                                              unsigned short* __restrict__ WT,
                                              int* __restrict__ zbase) {
  if (blockIdx.x >= 5) {
    int idx = (blockIdx.x - 5) * 512 + threadIdx.x * 4;
    *(int4*)(zbase + idx) = make_int4(0, 0, 0, 0);
    return;
  }
  const int s = blockIdx.x;
  const float* src = (s == 0) ? Wp : (s == 1) ? Wm : (s == 2) ? (Wm + HD * HD)
                     : (s == 3) ? Wu : (Wu + HD * HD);
  const int n = threadIdx.x;
  unsigned short* dst = WT + (size_t)s * HD * HD + (size_t)n * HD;
  for (int kc = 0; kc < HD; kc += 8) {
    u16x8 p;
#pragma unroll
    for (int j = 0; j < 8; ++j) p[j] = f2bf(src[(size_t)(kc + j) * HD + n]);
    *(u16x8*)(dst + kc) = p;
  }
}

// Heterogeneous: blocks 0..HB-1 = edge histogram (pos_e[e]=atomicAdd(deg[dst],1)),
// blocks HB.. = node projection (h0 = x@Wp+bp ; a = h0@Wm[:H] ; b = h0@Wm[H:]+bm).
// hist blocks run in the CU slots proj leaves idle (391 of 512) -> hist hides under proj.
__global__ __launch_bounds__(256, 2) void k_projhist(
    const float* __restrict__ x, const unsigned short* __restrict__ WT,
    const float* __restrict__ bp, const float* __restrict__ bm,
    unsigned short* __restrict__ h0, unsigned short* __restrict__ a,
    unsigned short* __restrict__ b, const int* __restrict__ edst,
    int* __restrict__ deg, int* __restrict__ pos_e) {
  __shared__ char Ssh[32768];
  __shared__ char Wsh[32768];
  if (blockIdx.x < HB) {
    for (int e = blockIdx.x * 256 + threadIdx.x; e < N_EDGES; e += HB * 256)
      pos_e[e] = atomicAdd(&deg[edst[e]], 1);
    return;
  }
  const int tid = threadIdx.x, lane = tid & 63, wid = tid >> 6;
  const int wr = wid >> 1, wc = wid & 1, l15 = lane & 15;
  const int bnode0 = (blockIdx.x - HB) * TILE_N;

  stage_xf(x, Ssh, bnode0, tid);
  stage_bf(WT, Wsh, 0, tid, false);  // WpT
  __syncthreads();

  bf16x8 A[4][4];
  f32x4 acc[4][4];
  load_A(Ssh, lane, wr, A);
#pragma unroll
  for (int ct = 0; ct < 4; ++ct) {
    float bv = bp[wc * 64 + ct * 16 + l15];
    f32x4 sv = {bv, bv, bv, bv};
#pragma unroll
    for (int rt = 0; rt < 4; ++rt) acc[rt][ct] = sv;
  }
  mfma_AB(A, Wsh, lane, wc, acc);          // h0
  __syncthreads();                          // x reads done
  scatter_acc(Ssh, lane, wr, wc, acc);      // h0 -> Ssh
  stage_bf(WT + 1 * HD * HD, Wsh, 0, tid, false);  // WmaT
  __syncthreads();
  copy_out(Ssh, h0, bnode0, tid);
  load_A(Ssh, lane, wr, A);                 // h0 frags (kept for a AND b)
#pragma unroll
  for (int ct = 0; ct < 4; ++ct) {
    f32x4 z = {0.f, 0.f, 0.f, 0.f};
#pragma unroll
    for (int rt = 0; rt < 4; ++rt) acc[rt][ct] = z;
  }
  mfma_AB(A, Wsh, lane, wc, acc);          // a
  __syncthreads();                          // copy_out(h0)+load_A done everywhere
  scatter_acc(Ssh, lane, wr, wc, acc);      // a -> Ssh
  stage_bf(WT + 2 * HD * HD, Wsh, 0, tid, false);  // WmbT
  __syncthreads();
  copy_out(Ssh, a, bnode0, tid);
#pragma unroll
  for (int ct = 0; ct < 4; ++ct) {
    float bv = bm[wc * 64 + ct * 16 + l15];
    f32x4 sv = {bv, bv, bv, bv};
#pragma unroll
    for (int rt = 0; rt < 4; ++rt) acc[rt][ct] = sv;
  }
  mfma_AB(A, Wsh, lane, wc, acc);          // b (A regs reused)
  __syncthreads();                          // copy_out(a) done everywhere
  scatter_acc(Ssh, lane, wr, wc, acc);      // b -> Ssh
  __syncthreads();
  copy_out(Ssh, b, bnode0, tid);
}

// scan1 (per-block reduce of deg) + scan2 (exclusive scan of block sums, done-counter)
__global__ __launch_bounds__(256) void k_scan12(const int* __restrict__ deg,
                                                int* __restrict__ bsum,
                                                int* __restrict__ boff,
                                                int* __restrict__ row_start,
                                                int* __restrict__ done2) {
  __shared__ int sh[256];
  __shared__ int amLast;
  int i = blockIdx.x * 256 + threadIdx.x;
  sh[threadIdx.x] = (i < N_NODES) ? deg[i] : 0;
  __syncthreads();
  for (int off = 128; off > 0; off >>= 1) {
    if (threadIdx.x < off) sh[threadIdx.x] += sh[threadIdx.x + off];
    __syncthreads();
  }
  if (threadIdx.x == 0) {
    bsum[blockIdx.x] = sh[0];
    __threadfence();
    amLast = (atomicAdd(done2, 1) == gridDim.x - 1) ? 1 : 0;
  }
  __syncthreads();
  if (amLast) {
    __threadfence();
    int t = threadIdx.x;
    int v = (t < NSCB) ? bsum[t] : 0;
    sh[t] = v;
    __syncthreads();
    for (int off = 1; off < 256; off <<= 1) {
      int add = (t >= off) ? sh[t - off] : 0;
      __syncthreads();
      sh[t] += add;
      __syncthreads();
    }
    if (t < NSCB) boff[t] = sh[t] - v;
    if (t == 255) row_start[N_NODES] = sh[255];
  }
}

__global__ __launch_bounds__(256) void k_scan3(const int* __restrict__ deg,
                                               const int* __restrict__ boff,
                                               int* __restrict__ row_start) {
  __shared__ int sh[256];
  int t = threadIdx.x;
  int i = blockIdx.x * 256 + t;
  int v = (i < N_NODES) ? deg[i] : 0;
  sh[t] = v;
  __syncthreads();
  for (int off = 1; off < 256; off <<= 1) {
    int add = (t >= off) ? sh[t - off] : 0;
    __syncthreads();
    sh[t] += add;
    __syncthreads();
  }
  if (i < N_NODES) row_start[i] = boff[blockIdx.x] + sh[t] - v;
}

// atomic-free scatter: slot precomputed in k_projhist
__global__ void k_scatter(const int* __restrict__ src, const int* __restrict__ dst,
                          const int* __restrict__ pos_e, const int* __restrict__ row_start,
                          int* __restrict__ es) {
  int e = blockIdx.x * 256 + threadIdx.x;
  if (e < N_EDGES) {
    int d = dst[e];
    es[row_start[d] + pos_e[e]] = src[e];
  }
}

// pooled[n] = mean over in-edges of relu(a[src] + b[n]); a,b,pooled bf16
__global__ __launch_bounds__(256) void k_agg(const unsigned short* __restrict__ a,
                                             const unsigned short* __restrict__ b,
                                             const int* __restrict__ es,
                                             const int* __restrict__ row_start,
                                             unsigned short* __restrict__ pooled) {
  const int node = blockIdx.x * 4 + (threadIdx.x >> 6);
  const int lane = threadIdx.x & 63;
  const int s = row_start[node];
  const int e = row_start[node + 1];
  const unsigned bu = ((const unsigned*)(b + (size_t)node * HD))[lane];
  const float bx = bf2f((unsigned short)(bu & 0xffffu));
  const float by = bf2f((unsigned short)(bu >> 16));
  float ax = 0.f, ay = 0.f;
  int i = s;
  for (; i + 8 <= e; i += 8) {
    unsigned av[8];
#pragma unroll
    for (int j = 0; j < 8; ++j)
      av[j] = ((const unsigned*)(a + (size_t)es[i + j] * HD))[lane];
#pragma unroll
    for (int j = 0; j < 8; ++j) {
      ax += fmaxf(bf2f((unsigned short)(av[j] & 0xffffu)) + bx, 0.f);
      ay += fmaxf(bf2f((unsigned short)(av[j] >> 16)) + by, 0.f);
    }
  }
  for (; i + 4 <= e; i += 4) {
    unsigned av[4];
#pragma unroll
    for (int j = 0; j < 4; ++j)
      av[j] = ((const unsigned*)(a + (size_t)es[i + j] * HD))[lane];
#pragma unroll
    for (int j = 0; j < 4; ++j) {
      ax += fmaxf(bf2f((unsigned short)(av[j] & 0xffffu)) + bx, 0.f);
      ay += fmaxf(bf2f((unsigned short)(av[j] >> 16)) + by, 0.f);
    }
  }
  for (; i < e; ++i) {
    unsigned a0 = ((const unsigned*)(a + (size_t)es[i] * HD))[lane];
    ax += fmaxf(bf2f((unsigned short)(a0 & 0xffffu)) + bx, 0.f);
    ay += fmaxf(bf2f((unsigned short)(a0 >> 16)) + by, 0.f);
  }
  const float inv = 1.f / fmaxf((float)(e - s), 1.f);
  unsigned o = (unsigned)f2bf(ax * inv) | ((unsigned)f2bf(ay * inv) << 16);
  ((unsigned*)(pooled + (size_t)node * HD))[lane] = o;
}

// upd = h0@Wu0 + pooled@Wu1 + bu ; hn = relu(h0+upd) ; LN ; graph-sum ;
// last block: out = (gsum/N)@Wd + bd.
__global__ __launch_bounds__(256, 2) void k_upd(
    const unsigned short* __restrict__ h0, const unsigned short* __restrict__ pooled,
    const unsigned short* __restrict__ WT, const float* __restrict__ bu,
    const float* __restrict__ gamma, const float* __restrict__ beta,
    const float* __restrict__ Wd, const float* __restrict__ bd,
    float* __restrict__ gsum, int* __restrict__ done, float* __restrict__ out) {
  __shared__ char Ssh[32768];
  __shared__ char Wsh[32768];
  __shared__ int lastflag;
  const int tid = threadIdx.x, lane = tid & 63, wid = tid >> 6;
  const int wr = wid >> 1, wc = wid & 1, l15 = lane & 15, l4 = lane >> 4;
  const int bnode0 = blockIdx.x * TILE_N;

  stage_bf(pooled, Ssh, bnode0, tid, true);
  stage_bf(WT + 4 * HD * HD, Wsh, 0, tid, false);  // Wu1T
  __syncthreads();

  bf16x8 A[4][4];
  f32x4 acc[4][4];
  load_A(Ssh, lane, wr, A);
#pragma unroll
  for (int ct = 0; ct < 4; ++ct) {
    float bv = bu[wc * 64 + ct * 16 + l15];
    f32x4 sv = {bv, bv, bv, bv};
#pragma unroll
    for (int rt = 0; rt < 4; ++rt) acc[rt][ct] = sv;
  }
  mfma_AB(A, Wsh, lane, wc, acc);  // pooled@Wu1 + bu
  __syncthreads();
  stage_bf(h0, Ssh, bnode0, tid, true);
  stage_bf(WT + 3 * HD * HD, Wsh, 0, tid, false);  // Wu0T
  __syncthreads();
  load_A(Ssh, lane, wr, A);
  mfma_AB(A, Wsh, lane, wc, acc);  // += h0@Wu0
  __syncthreads();                 // Wsh free for partials

  // residual + relu + LayerNorm + masked graph partial
  float rsum[4][4], rsq[4][4];
#pragma unroll
  for (int rt = 0; rt < 4; ++rt)
#pragma unroll
    for (int e = 0; e < 4; ++e) {
      int r = wr * 64 + rt * 16 + l4 * 4 + e;
      float srow = 0.f, qrow = 0.f;
#pragma unroll
      for (int ct = 0; ct < 4; ++ct) {
        int c = wc * 64 + ct * 16 + l15;
        float hv = bf2f(*(const unsigned short*)(Ssh + swzb(r, c >> 3) + (c & 7) * 2));
        float v = fmaxf(hv + acc[rt][ct][e], 0.f);
        acc[rt][ct][e] = v;
        srow += v;
        qrow += v * v;
      }
#pragma unroll
      for (int m = 1; m < 16; m <<= 1) {
        srow += __shfl_xor(srow, m);
        qrow += __shfl_xor(qrow, m);
      }
      rsum[rt][e] = srow;
      rsq[rt][e] = qrow;
    }
  float* pS = (float*)Wsh;          // [128][2]
  float* pQ = (float*)(Wsh + 1024);
  if (l15 == 0) {
#pragma unroll
    for (int rt = 0; rt < 4; ++rt)
#pragma unroll
      for (int e = 0; e < 4; ++e) {
        int r = wr * 64 + rt * 16 + l4 * 4 + e;
        pS[r * 2 + wc] = rsum[rt][e];
        pQ[r * 2 + wc] = rsq[rt][e];
      }
  }
  __syncthreads();

  float g4[4], b4[4];
#pragma unroll
  for (int ct = 0; ct < 4; ++ct) {
    int c = wc * 64 + ct * 16 + l15;
    g4[ct] = gamma[c];
    b4[ct] = beta[c];
  }
  float gp[4] = {0.f, 0.f, 0.f, 0.f};
#pragma unroll
  for (int rt = 0; rt < 4; ++rt)
#pragma unroll
    for (int e = 0; e < 4; ++e) {
      int r = wr * 64 + rt * 16 + l4 * 4 + e;
      float s = pS[r * 2] + pS[r * 2 + 1];
      float q = pQ[r * 2] + pQ[r * 2 + 1];
      float mu = s * (1.f / 128.f);
      float var = q * (1.f / 128.f) - mu * mu;
      float rs = rsqrtf(var + 1e-6f);
      bool valid = (bnode0 + r) < N_NODES;
#pragma unroll
      for (int ct = 0; ct < 4; ++ct) {
        float v = (acc[rt][ct][e] - mu) * rs * g4[ct] + b4[ct];
        if (valid) gp[ct] += v;
      }
    }
#pragma unroll
  for (int ct = 0; ct < 4; ++ct) {
    gp[ct] += __shfl_xor(gp[ct], 16);
    gp[ct] += __shfl_xor(gp[ct], 32);
  }
  if (lane < 16) {
#pragma unroll
    for (int ct = 0; ct < 4; ++ct) atomicAdd(&gsum[wc * 64 + ct * 16 + lane], gp[ct]);
  }

  // last block computes the graph head
  __threadfence();
  __syncthreads();
  if (tid == 0) lastflag = (atomicAdd(done, 1) == gridDim.x - 1) ? 1 : 0;
  __syncthreads();
  if (lastflag) {
    __threadfence();
    if (tid < 32) {
      float acc2 = bd[tid];
      const float invN = 1.f / (float)N_NODES;
      for (int d = 0; d < HD; ++d) acc2 = fmaf(gsum[d] * invN, Wd[d * 32 + tid], acc2);
      out[tid] = acc2;
    }
  }
}

extern "C" void kernel_launch(void* const* d_in, const int* in_sizes, int n_in,
                              void* d_out, int out_size, void* d_ws, size_t ws_size,
                              hipStream_t stream) {
  (void)in_sizes; (void)n_in; (void)out_size; (void)ws_size;
  const float* x    = (const float*)d_in[0];
  const int* esrc   = (const int*)d_in[1];
  const int* edst   = (const int*)d_in[2];
  const float* Wp   = (const float*)d_in[3];
  const float* bp   = (const float*)d_in[4];
  const float* Wm   = (const float*)d_in[5];
  const float* bm   = (const float*)d_in[6];
  const float* Wu   = (const float*)d_in[7];
  const float* bu   = (const float*)d_in[8];
  const float* gam  = (const float*)d_in[9];
  const float* bet  = (const float*)d_in[10];
  const float* Wd   = (const float*)d_in[11];
  const float* bd   = (const float*)d_in[12];
  float* out = (float*)d_out;

  char* ws = (char*)d_ws;
  size_t off = 0;
  unsigned short* WT     = (unsigned short*)(ws + off); off += 5 * (size_t)HD * HD * 2;  // 160KB
  unsigned short* h0     = (unsigned short*)(ws + off); off += (size_t)N_NODES * HD * 2;
  unsigned short* a      = (unsigned short*)(ws + off); off += (size_t)N_NODES * HD * 2;
  unsigned short* b      = (unsigned short*)(ws + off); off += (size_t)N_NODES * HD * 2;
  unsigned short* pooled = (unsigned short*)(ws + off); off += (size_t)N_NODES * HD * 2;
  int* es    = (int*)(ws + off); off += (size_t)N_EDGES * 4;
  int* pos_e = (int*)(ws + off); off += (size_t)N_EDGES * 4;
  // zero region: deg[50000] + gsum[128] + done[1] + done2[1] + pad = 50176 ints
  int* zbase = (int*)(ws + off);
  int* deg   = zbase;
  float* gsum = (float*)(zbase + N_NODES);
  int* done  = zbase + N_NODES + 128;
  int* done2 = zbase + N_NODES + 129;
  off += (size_t)50176 * 4;
  int* row_start = (int*)(ws + off); off += (size_t)(N_NODES + 1) * 4;
  int* bsum = (int*)(ws + off); off += (size_t)NSCB * 4;
  int* boff = (int*)(ws + off); off += (size_t)NSCB * 4;

  k_prew<<<103, 128, 0, stream>>>(Wp, Wm, Wu, WT, zbase);
  k_projhist<<<HB + NTILE, 256, 0, stream>>>(x, WT, bp, bm, h0, a, b, edst, deg, pos_e);
  k_scan12<<<NSCB, 256, 0, stream>>>(deg, bsum, boff, row_start, done2);
  k_scan3<<<NSCB, 256, 0, stream>>>(deg, boff, row_start);
  k_scatter<<<(N_EDGES + 255) / 256, 256, 0, stream>>>(esrc, edst, pos_e, row_start, es);
  k_agg<<<N_NODES / 4, 256, 0, stream>>>(a, b, es, row_start, pooled);
  k_upd<<<NTILE, 256, 0, stream>>>(h0, pooled, WT, bu, gam, bet, Wd, bd, gsum, done, out);
}